// Round 3
// baseline (1730.246 us; speedup 1.0000x reference)
//
#include <hip/hip_runtime.h>
#include <math.h>

typedef unsigned int uint;
typedef unsigned short ushort;
typedef unsigned long long u64;
typedef __attribute__((ext_vector_type(8))) short short8;
typedef __attribute__((ext_vector_type(4))) float f32x4;

// Problem: z (16,256,32,32) fp32, emb (8192,256) fp32. N=16384 rows, K=256, C=8192 codes.
// out (fp32): [0,4194304) z_q (b,c,h,w) | [4194304] loss | [4194305,+16384) idx as float
//
// Exact-argmin scheme: bf16 MFMA screening (deterministic err bound |d~-d| <= 3.3e-4 worst row)
// + exact fp32 rescore of candidates within margin -> u64 (grid-score|idx) atomicMin.
//
// ws: zt fp32[16384][256] @0 | zbf bf16[n][k] @16M | ebf bf16[c][k] @24M | sumz @28M
//     maxdot u32[16384] | best u64[16384] | cand u32[512K] | cnt | loss   (~30.3 MB total)
#define WS_ZT   0ull
#define WS_ZBF  16777216ull
#define WS_EBF  25165824ull
#define WS_SUMZ 29360128ull
#define WS_MAXD 29425664ull
#define WS_BEST 29491200ull
#define WS_CAND 29622272ull
#define WS_CNT  31719424ull

#define CAP 524288u
#define DOT_MARGIN 6e-4f   // d-margin 1.2e-3 > 2*3.3e-4 worst-case + grid slack

__device__ __forceinline__ ushort f2bf(float f) {           // RNE fp32->bf16
  uint b = __float_as_uint(f);
  b += 0x7fffu + ((b >> 16) & 1u);
  return (ushort)(b >> 16);
}
__device__ __forceinline__ uint ford(float f) {             // orderable uint
  uint b = __float_as_uint(f);
  return (b & 0x80000000u) ? ~b : (b | 0x80000000u);
}
__device__ __forceinline__ float ord2f(uint u) {
  uint b = (u & 0x80000000u) ? (u & 0x7fffffffu) : ~u;
  return __uint_as_float(b);
}

// ---------------- prep: zt[n][k] fp32 + zbf[n][k] bf16 (transpose from z[b][k][hw])
__global__ __launch_bounds__(256) void prep_z(const float* __restrict__ z,
                                              float* __restrict__ zt,
                                              ushort* __restrict__ zbf) {
  __shared__ float tile[64][65];
  const int bid = blockIdx.x;
  const int kt = bid & 3, hwt = (bid >> 2) & 15, b = bid >> 6;
  const int t = threadIdx.x, lane = t & 63, grp = t >> 6;
  const float* src = z + b * 262144 + (kt * 64) * 1024 + hwt * 64;
  for (int kk = grp; kk < 64; kk += 4)
    tile[kk][lane] = src[kk * 1024 + lane];                 // coalesced over hw
  __syncthreads();
  for (int rr = grp; rr < 64; rr += 4) {
    const int n = b * 1024 + hwt * 64 + rr;
    const float v = tile[lane][rr];
    zt[n * 256 + kt * 64 + lane] = v;                       // coalesced over k
    zbf[n * 256 + kt * 64 + lane] = f2bf(v);
  }
}

// ---------------- prep: ebf[c][k] bf16 straight convert
__global__ __launch_bounds__(256) void prep_e(const float* __restrict__ emb,
                                              ushort* __restrict__ ebf) {
  const int i = (blockIdx.x * 256 + threadIdx.x) * 4;
  const float4 v = *(const float4*)(emb + i);
  ushort4 o; o.x = f2bf(v.x); o.y = f2bf(v.y); o.z = f2bf(v.z); o.w = f2bf(v.w);
  *(ushort4*)(ebf + i) = o;
}

// ---------------- sumz[n] = ||z_n||^2, sequential-k fp32 (proven numerics)
__global__ __launch_bounds__(256) void zsum_kernel(const float* __restrict__ z,
                                                   float* __restrict__ sumz) {
  const int n = (blockIdx.x << 8) + threadIdx.x;
  const int b = n >> 10, hw = n & 1023;
  const float* zb = z + b * 262144 + hw;
  float s = 0.f;
#pragma unroll 8
  for (int c = 0; c < 256; ++c) { const float v = zb[c << 10]; s += v * v; }
  sumz[n] = s;
}

// ---------------- bf16 MFMA GEMM, 128x128 block tile, B-panel (128x256) LDS-resident.
// PASS 1: per-row atomicMax of dot. PASS 2: emit candidates >= max - margin.
// Bs: 64 KB exactly, XOR-swizzled 16B slots (conflict-free b128 reads, no padding).
template <int PASS>
__global__ __launch_bounds__(256, 2) void gemm_pass(const ushort* __restrict__ zbf,
                                                    const ushort* __restrict__ ebf,
                                                    uint* __restrict__ maxdot,
                                                    uint* __restrict__ cand,
                                                    uint* __restrict__ cnt) {
  __shared__ ushort Bs[32768];
  const int t = threadIdx.x;
  const int bid = blockIdx.x;
  const int xcd = bid & 7, s = bid >> 3;
  const int rowg = s >> 3;                 // 0..7  (2048 rows each)
  const int colb = (s & 7) * 8 + xcd;      // 0..63 -> XCD-local col groups
  const int c0 = colb << 7;

  { // stage B panel once: ebf[c0..c0+128)[0..256) -> swizzled LDS
    const int col_s = t >> 1, half = t & 1;
    const ushort* src = ebf + (c0 + col_s) * 256 + half * 128;
    const int sw_hi = (col_s >> 2) & 7, sw_lo = col_s & 3;
#pragma unroll
    for (int j = 0; j < 16; ++j) {
      const int k0 = half * 4 + (j >> 2), q = j & 3;
      const int slot = col_s * 32 + ((k0 ^ sw_hi) << 2) + (q ^ sw_lo);
      *(short8*)&Bs[slot * 8] = *(const short8*)(src + (j >> 2) * 32 + q * 8);
    }
  }
  __syncthreads();

  const int w = t >> 6, lane = t & 63;
  const int wr = w & 1, wc = w >> 1;       // 2x2 wave grid (64x64 each)
  const int m16 = lane & 15, q = lane >> 4;

  for (int rs = 0; rs < 16; ++rs) {
    const int n0 = rowg * 2048 + rs * 128;
    f32x4 acc[4][4];
#pragma unroll
    for (int i = 0; i < 4; ++i)
#pragma unroll
      for (int j = 0; j < 4; ++j) acc[i][j] = {0.f, 0.f, 0.f, 0.f};

    // A direct from global: lane holds A[m=lane&15][k=q*8+j] per 16x16 tile
    const ushort* abase = zbf + (n0 + wr * 64 + m16) * 256 + q * 8;
    short8 a_cur[4], a_nxt[4];
#pragma unroll
    for (int i = 0; i < 4; ++i) a_cur[i] = *(const short8*)(abase + i * 4096);

    for (int k0 = 0; k0 < 8; ++k0) {
      if (k0 < 7) {
#pragma unroll
        for (int i = 0; i < 4; ++i)
          a_nxt[i] = *(const short8*)(abase + i * 4096 + (k0 + 1) * 32);
      }
      short8 b[4];
#pragma unroll
      for (int j = 0; j < 4; ++j) {
        const int col = wc * 64 + j * 16 + m16;
        const int slot = col * 32 + ((k0 ^ ((col >> 2) & 7)) << 2) + (q ^ (col & 3));
        b[j] = *(const short8*)&Bs[slot * 8];
      }
#pragma unroll
      for (int i = 0; i < 4; ++i)
#pragma unroll
        for (int j = 0; j < 4; ++j)
          acc[i][j] = __builtin_amdgcn_mfma_f32_16x16x32_bf16(a_cur[i], b[j], acc[i][j], 0, 0, 0);
#pragma unroll
      for (int i = 0; i < 4; ++i) a_cur[i] = a_nxt[i];
    }

    // D layout: row = q*4+reg (+i*16+wr*64), col = m16 (+j*16+wc*64)
    const int rbase = n0 + wr * 64 + q * 4;
    if (PASS == 1) {
#pragma unroll
      for (int i = 0; i < 4; ++i)
#pragma unroll
        for (int reg = 0; reg < 4; ++reg) {
          float m = fmaxf(fmaxf(acc[i][0][reg], acc[i][1][reg]),
                          fmaxf(acc[i][2][reg], acc[i][3][reg]));
          m = fmaxf(m, __shfl_xor(m, 1, 64));
          m = fmaxf(m, __shfl_xor(m, 2, 64));
          m = fmaxf(m, __shfl_xor(m, 4, 64));
          m = fmaxf(m, __shfl_xor(m, 8, 64));
          if (m16 == 0) atomicMax(&maxdot[rbase + i * 16 + reg], ford(m));
        }
    } else {
#pragma unroll
      for (int i = 0; i < 4; ++i)
#pragma unroll
        for (int reg = 0; reg < 4; ++reg) {
          const float thr = ord2f(maxdot[rbase + i * 16 + reg]) - DOT_MARGIN;
#pragma unroll
          for (int j = 0; j < 4; ++j) {
            if (acc[i][j][reg] >= thr) {
              const uint pos = atomicAdd(cnt, 1u);
              if (pos < CAP)
                cand[pos] = ((uint)(rbase + i * 16 + reg) << 13) |
                            (uint)(c0 + wc * 64 + j * 16 + m16);
            }
          }
        }
    }
  }
}

// ---------------- exact fp32 rescore of candidates (sequential-k, matches proven numerics)
__global__ __launch_bounds__(256) void rescore(const float* __restrict__ zt,
                                               const float* __restrict__ emb,
                                               const float* __restrict__ sumz,
                                               const uint* __restrict__ cand,
                                               const uint* __restrict__ cnt,
                                               u64* __restrict__ best) {
  const uint tid = blockIdx.x * 256 + threadIdx.x;
  uint n_c = *cnt; if (n_c > CAP) n_c = CAP;
  if (tid >= n_c) return;
  const uint u = cand[tid];
  const int n = u >> 13, c = u & 8191;
  const float4* za = (const float4*)(zt + n * 256);
  const float4* ea = (const float4*)(emb + c * 256);
  float sdot = 0.f;
#pragma unroll 8
  for (int k = 0; k < 64; ++k) {
    const float4 a = za[k], e = ea[k];
    sdot = fmaf(a.x, e.x, sdot); sdot = fmaf(a.y, e.y, sdot);
    sdot = fmaf(a.z, e.z, sdot); sdot = fmaf(a.w, e.w, sdot);
  }
  const float d = sumz[n] - 2.f * sdot;
  const u64 key = ((u64)ford(d) << 32) | (uint)c;
  atomicMin(&best[n], key);                 // min score, tie -> lowest idx
}

// ---------------- gather z_q, idx, loss (unchanged from passing round)
__global__ __launch_bounds__(256) void gather_kernel(const float* __restrict__ z,
                                                     const float* __restrict__ emb,
                                                     const u64* __restrict__ best,
                                                     float* __restrict__ out,
                                                     double* __restrict__ loss_acc) {
  const int t = threadIdx.x;
  const int n0 = blockIdx.x << 6;
  const int hw_l = t & 63;
  const int n = n0 + hw_l;
  const int idx = (int)(best[n] & 0xffffffffull);
  const int b_i = n >> 10;
  const int hw = n & 1023;
  const int c0 = t >> 6;
  const float* zb = z + b_i * 262144 + hw;
  float* ob = out + b_i * 262144 + hw;
  const float* eb = emb + idx * 256;
  float lsum = 0.f;
#pragma unroll 4
  for (int c = c0; c < 256; c += 4) {
    const float ev = eb[c];
    const float zv = zb[c << 10];
    ob[c << 10] = ev;
    const float d = ev - zv;
    lsum += d * d;
  }
  if (c0 == 0) out[4194305 + n] = (float)idx;
#pragma unroll
  for (int off = 32; off; off >>= 1) lsum += __shfl_down(lsum, off, 64);
  __shared__ double wsum[4];
  if ((t & 63) == 0) wsum[t >> 6] = (double)lsum;
  __syncthreads();
  if (t == 0) atomicAdd(loss_acc, wsum[0] + wsum[1] + wsum[2] + wsum[3]);
}

__global__ void finalize_kernel(const double* __restrict__ loss_acc, float* __restrict__ out) {
  if (threadIdx.x == 0) out[4194304] = (float)(1.25 * (*loss_acc) / 4194304.0);
}

// ---------------- launch
extern "C" void kernel_launch(void* const* d_in, const int* in_sizes, int n_in,
                              void* d_out, int out_size, void* d_ws, size_t ws_size,
                              hipStream_t stream) {
  const float* z = (const float*)d_in[0];
  const float* emb = (const float*)d_in[1];
  float* out = (float*)d_out;
  char* ws = (char*)d_ws;
  float* zt = (float*)(ws + WS_ZT);
  ushort* zbf = (ushort*)(ws + WS_ZBF);
  ushort* ebf = (ushort*)(ws + WS_EBF);
  float* sumz = (float*)(ws + WS_SUMZ);
  uint* maxd = (uint*)(ws + WS_MAXD);
  u64* best = (u64*)(ws + WS_BEST);
  uint* cand = (uint*)(ws + WS_CAND);
  uint* cnt = (uint*)(ws + WS_CNT);
  double* loss_acc = (double*)(ws + WS_CNT + 8);

  hipMemsetAsync(maxd, 0, 65536, stream);                 // ford(-inf) floor
  hipMemsetAsync(best, 0xFF, 131072, stream);             // u64 max
  hipMemsetAsync(cnt, 0, 16, stream);                     // cnt + loss
  prep_z<<<1024, 256, 0, stream>>>(z, zt, zbf);
  prep_e<<<2048, 256, 0, stream>>>(emb, ebf);
  zsum_kernel<<<64, 256, 0, stream>>>(z, sumz);
  gemm_pass<1><<<512, 256, 0, stream>>>(zbf, ebf, maxd, cand, cnt);
  gemm_pass<2><<<512, 256, 0, stream>>>(zbf, ebf, maxd, cand, cnt);
  rescore<<<2048, 256, 0, stream>>>(zt, emb, sumz, cand, cnt, best);
  gather_kernel<<<256, 256, 0, stream>>>(z, emb, best, out, loss_acc);
  finalize_kernel<<<1, 64, 0, stream>>>(loss_acc, out);
}